// Round 9
// baseline (825.463 us; speedup 1.0000x reference)
//
#include <hip/hip_runtime.h>
#include <math.h>

static constexpr float AFWD = 0.999f;
static constexpr float EPS  = 1e-5f;

typedef float vfloat4 __attribute__((ext_vector_type(4)));

#define NROWS 32   // rows per chunk held in registers (128 VGPRs of data)

// ---------------- init: zero the lookback state flags -----------------------
__global__ void init_state(int* __restrict__ state, int count) {
    const int i = blockIdx.x * blockDim.x + threadIdx.x;
    if (i < count) state[i] = 0;
}

// ---------------- single-pass decoupled-lookback online-norm ----------------
// Block (c,g): bid = c*G + g. 256 threads x 4 cols = COLS=1024 columns.
// state: 0 = nothing, 1 = local aggregate ready, 2 = inclusive ready.
// Carry map per chunk (A=a^n, B=A(1-a), W=A(1-A)):
//   mu'  = A*mu + S
//   var' = A*var + T0 - 2B*E*mu + W*mu^2
// General map (M,S | P,Q,R,U): mu'=M*mu+S ; var'=P*var+Q+R*mu+U*mu^2 — closed
// under composition, so lookback composes predecessors' local maps exactly.
__global__ __launch_bounds__(256, 2) void onlnorm_lookback(
    const float* __restrict__ x,
    const float* __restrict__ mu0, const float* __restrict__ var0,
    float* __restrict__ out,
    int* __restrict__ state,
    float* __restrict__ locals,   // [C*G][3][COLS]  (S, T0, E)
    float* __restrict__ incl,     // [C*G][2][COLS]  (mu_out, var_out)
    int n, int L, int G, int COLS,
    float A, float B, float W)
{
    const float a = AFWD, b = 1.0f - AFWD, ab = AFWD * (1.0f - AFWD);
    const int bid = blockIdx.x;
    const int c = bid / G, g = bid % G;
    const int col = g * COLS + (int)threadIdx.x * 4;

    // ---- 1. load this chunk into registers (32 independent loads) ----
    const float* xp = x + (size_t)c * (size_t)n * L + col;
    vfloat4 xr[NROWS];
    #pragma unroll
    for (int i = 0; i < NROWS; ++i)
        xr[i] = *reinterpret_cast<const vfloat4*>(xp + (size_t)i * L);

    // ---- 2. chunk-local aggregates (zero carry) ----
    vfloat4 S4 = {0,0,0,0}, T4 = {0,0,0,0}, E4 = {0,0,0,0};
    #pragma unroll
    for (int i = 0; i < NROWS; ++i) {
        const vfloat4 d = xr[i] - S4;
        E4 += d;
        T4 = a*T4 + ab*d*d;
        S4 += b*d;
    }

    // ---- 3. publish local aggregate ----
    {
        const size_t lb = ((size_t)bid * 3) * COLS + (size_t)threadIdx.x * 4;
        *reinterpret_cast<vfloat4*>(locals + lb)            = S4;
        *reinterpret_cast<vfloat4*>(locals + lb + COLS)     = T4;
        *reinterpret_cast<vfloat4*>(locals + lb + 2*COLS)   = E4;
        __threadfence();
        __syncthreads();
        if (threadIdx.x == 0)
            __hip_atomic_store(&state[bid], 1, __ATOMIC_RELEASE, __HIP_MEMORY_SCOPE_AGENT);
    }

    // ---- 4. resolve carry-in via lookback ----
    vfloat4 mu, var;
    if (c == 0) {
        mu  = *reinterpret_cast<const vfloat4*>(mu0 + col);
        var = *reinterpret_cast<const vfloat4*>(var0 + col);
    } else {
        vfloat4 Mm = {1,1,1,1}, Ss = {0,0,0,0};
        vfloat4 Pp = {1,1,1,1}, Qq = {0,0,0,0}, Rr = {0,0,0,0}, Uu = {0,0,0,0};
        int p = c - 1;
        for (;;) {
            const int pid = p * G + g;
            int st;
            do {
                st = __hip_atomic_load(&state[pid], __ATOMIC_ACQUIRE, __HIP_MEMORY_SCOPE_AGENT);
                if (st == 0) __builtin_amdgcn_s_sleep(8);
            } while (st == 0);
            if (st == 2) {
                const size_t ib = ((size_t)pid * 2) * COLS + (size_t)threadIdx.x * 4;
                const vfloat4 pmu  = *reinterpret_cast<const vfloat4*>(incl + ib);
                const vfloat4 pvar = *reinterpret_cast<const vfloat4*>(incl + ib + COLS);
                var = Pp*pvar + Qq + Rr*pmu + Uu*pmu*pmu;
                mu  = Mm*pmu + Ss;
                break;
            } else {
                const size_t pb = ((size_t)pid * 3) * COLS + (size_t)threadIdx.x * 4;
                const vfloat4 S1 = *reinterpret_cast<const vfloat4*>(locals + pb);
                const vfloat4 Q1 = *reinterpret_cast<const vfloat4*>(locals + pb + COLS);
                const vfloat4 E1 = *reinterpret_cast<const vfloat4*>(locals + pb + 2*COLS);
                const vfloat4 R1 = -2.0f*B*E1;
                // ACC = ACC ∘ F_p  (map1 = F_p = (A,S1 | A,Q1,R1,W), map2 = ACC)
                const vfloat4 nM = Mm*A;
                const vfloat4 nS = Mm*S1 + Ss;
                const vfloat4 nP = Pp*A;
                const vfloat4 nQ = Pp*Q1 + Qq + Rr*S1 + Uu*S1*S1;
                const vfloat4 nR = Pp*R1 + Rr*A + 2.0f*Uu*A*S1;
                const vfloat4 nU = Pp*W + Uu*A*A;
                Mm = nM; Ss = nS; Pp = nP; Qq = nQ; Rr = nR; Uu = nU;
                if (p == 0) {
                    const vfloat4 imu  = *reinterpret_cast<const vfloat4*>(mu0 + col);
                    const vfloat4 ivar = *reinterpret_cast<const vfloat4*>(var0 + col);
                    var = Pp*ivar + Qq + Rr*imu + Uu*imu*imu;
                    mu  = Mm*imu + Ss;
                    break;
                }
                --p;
            }
        }
    }

    // ---- 5. publish inclusive (apply own map) ----
    {
        const vfloat4 mout = A*mu + S4;
        const vfloat4 vout = A*var + T4 - 2.0f*B*E4*mu + W*mu*mu;
        const size_t ib = ((size_t)bid * 2) * COLS + (size_t)threadIdx.x * 4;
        *reinterpret_cast<vfloat4*>(incl + ib)        = mout;
        *reinterpret_cast<vfloat4*>(incl + ib + COLS) = vout;
        __threadfence();
        __syncthreads();
        if (threadIdx.x == 0)
            __hip_atomic_store(&state[bid], 2, __ATOMIC_RELEASE, __HIP_MEMORY_SCOPE_AGENT);
    }

    // ---- 6. normalize from registers, nt-store ----
    float* op = out + (size_t)c * (size_t)n * L + col;
    vfloat4 m = mu, v = var;
    #pragma unroll
    for (int i = 0; i < NROWS; ++i) {
        const vfloat4 d = xr[i] - m;
        vfloat4 rs;
        rs.x = rsqrtf(v.x + EPS); rs.y = rsqrtf(v.y + EPS);
        rs.z = rsqrtf(v.z + EPS); rs.w = rsqrtf(v.w + EPS);
        const vfloat4 ov = d * rs;
        v = a*v + ab*d*d;
        m += b*d;
        __builtin_nontemporal_store(ov, reinterpret_cast<vfloat4*>(op + (size_t)i * L));
    }
}

// ===================== fallback 3-pass path (R8, known-good) ================
__global__ __launch_bounds__(256) void onlnorm_pass1(
    const float* __restrict__ x, float* __restrict__ Sv,
    float* __restrict__ T0v, float* __restrict__ Ev, int n, int L)
{
    const int chunk = blockIdx.y;
    const int col = (blockIdx.x * blockDim.x + threadIdx.x) * 4;
    if (col >= L) return;
    const float a = AFWD, b = 1.0f - AFWD, ab = AFWD * (1.0f - AFWD);
    const float* xp = x + (size_t)chunk * (size_t)n * L + col;
    float m0=0.f,m1=0.f,m2=0.f,m3=0.f, t0=0.f,t1=0.f,t2=0.f,t3=0.f;
    float e0=0.f,e1=0.f,e2=0.f,e3=0.f;
    for (int i = 0; i < n; ++i) {
        const float4 xv = *reinterpret_cast<const float4*>(xp + (size_t)i * L);
        float d;
        d = xv.x - m0; e0 += d; t0 = a*t0 + ab*d*d; m0 += b*d;
        d = xv.y - m1; e1 += d; t1 = a*t1 + ab*d*d; m1 += b*d;
        d = xv.z - m2; e2 += d; t2 = a*t2 + ab*d*d; m2 += b*d;
        d = xv.w - m3; e3 += d; t3 = a*t3 + ab*d*d; m3 += b*d;
    }
    const size_t base = (size_t)chunk * L + col;
    *reinterpret_cast<float4*>(Sv  + base) = make_float4(m0,m1,m2,m3);
    *reinterpret_cast<float4*>(T0v + base) = make_float4(t0,t1,t2,t3);
    *reinterpret_cast<float4*>(Ev  + base) = make_float4(e0,e1,e2,e3);
}

__global__ __launch_bounds__(128) void onlnorm_pass2(
    const float* __restrict__ Sv, const float* __restrict__ T0v,
    const float* __restrict__ Ev, const float* __restrict__ mu0,
    const float* __restrict__ var0, float* __restrict__ muin,
    float* __restrict__ varin, int C, int L, float A, float B, float W)
{
    const int col = blockIdx.x * blockDim.x + threadIdx.x;
    if (col >= L) return;
    float mu = mu0[col], var = var0[col];
    for (int c0 = 0; c0 < C; ++c0) {
        const size_t idx = (size_t)c0 * L + col;
        muin[idx] = mu; varin[idx] = var;
        const float s = Sv[idx], t = T0v[idx], e = Ev[idx];
        var = A*var + t - 2.0f*B*mu*e + W*mu*mu;
        mu  = A*mu + s;
    }
}

__global__ __launch_bounds__(256) void onlnorm_pass3(
    const float* __restrict__ x, const float* __restrict__ muin,
    const float* __restrict__ varin, float* __restrict__ out, int n, int L)
{
    const int chunk = blockIdx.y;
    const int col = (blockIdx.x * blockDim.x + threadIdx.x) * 4;
    if (col >= L) return;
    const float a = AFWD, b = 1.0f - AFWD, ab = AFWD * (1.0f - AFWD);
    const size_t cbase = (size_t)chunk * L + col;
    const float4 muv  = *reinterpret_cast<const float4*>(muin  + cbase);
    const float4 varv = *reinterpret_cast<const float4*>(varin + cbase);
    float m0=muv.x, m1=muv.y, m2=muv.z, m3=muv.w;
    float v0=varv.x, v1=varv.y, v2=varv.z, v3=varv.w;
    const float* xp = x   + (size_t)chunk * (size_t)n * L + col;
    float*       op = out + (size_t)chunk * (size_t)n * L + col;
    for (int i = 0; i < n; ++i) {
        const float4 xv = *reinterpret_cast<const float4*>(xp + (size_t)i * L);
        vfloat4 ov; float d;
        d = xv.x - m0; ov.x = d * rsqrtf(v0 + EPS); v0 = a*v0 + ab*d*d; m0 += b*d;
        d = xv.y - m1; ov.y = d * rsqrtf(v1 + EPS); v1 = a*v1 + ab*d*d; m1 += b*d;
        d = xv.z - m2; ov.z = d * rsqrtf(v2 + EPS); v2 = a*v2 + ab*d*d; m2 += b*d;
        d = xv.w - m3; ov.w = d * rsqrtf(v3 + EPS); v3 = a*v3 + ab*d*d; m3 += b*d;
        __builtin_nontemporal_store(ov, reinterpret_cast<vfloat4*>(op + (size_t)i * L));
    }
}

extern "C" void kernel_launch(void* const* d_in, const int* in_sizes, int n_in,
                              void* d_out, int out_size, void* d_ws, size_t ws_size,
                              hipStream_t stream) {
    const float* x    = (const float*)d_in[0];
    const float* mu0  = (const float*)d_in[1];
    const float* var0 = (const float*)d_in[2];
    float* out = (float*)d_out;

    const int L = in_sizes[1];          // 4096
    const int N = in_sizes[0] / L;      // 8192

    const int COLS = 1024;              // 256 threads x 4 cols
    const bool ok = (L % COLS == 0) && (N % NROWS == 0);

    if (ok) {
        const int G = L / COLS;         // 4
        const int C = N / NROWS;        // 256
        const int nblk = C * G;         // 1024

        const size_t need = (size_t)nblk * sizeof(int)
                          + (size_t)nblk * 5 * COLS * sizeof(float) + 256;
        if (need <= ws_size) {
            int*   state  = (int*)d_ws;
            float* locals = (float*)((char*)d_ws + ((size_t)nblk * sizeof(int) + 255 & ~(size_t)255));
            float* incl   = locals + (size_t)nblk * 3 * COLS;

            const double a  = (double)AFWD;
            const double An = pow(a, (double)NROWS);
            const float A = (float)An;
            const float B = (float)(An * (1.0 - a));
            const float W = (float)(An * (1.0 - An));

            init_state<<<dim3((nblk + 255) / 256), dim3(256), 0, stream>>>(state, nblk);
            onlnorm_lookback<<<dim3(nblk), dim3(256), 0, stream>>>(
                x, mu0, var0, out, state, locals, incl,
                NROWS, L, G, COLS, A, B, W);
            return;
        }
    }

    // -------- fallback: R8 3-pass --------
    int C = 256;
    while (C > 1 && ((size_t)5 * (size_t)C * L * sizeof(float) > ws_size ||
                     (N % C) != 0))
        C >>= 1;
    const int n = N / C;

    float* Sv    = (float*)d_ws;
    float* T0v   = Sv    + (size_t)C * L;
    float* Ev    = T0v   + (size_t)C * L;
    float* muin  = Ev    + (size_t)C * L;
    float* varin = muin  + (size_t)C * L;

    const double a  = (double)AFWD;
    const double An = pow(a, (double)n);
    const float A = (float)An;
    const float B = (float)(An * (1.0 - a));
    const float W = (float)(An * (1.0 - An));

    const dim3 blk(256);
    const dim3 g1((L / 4 + 255) / 256, C);
    onlnorm_pass1<<<g1, blk, 0, stream>>>(x, Sv, T0v, Ev, n, L);
    onlnorm_pass2<<<dim3((L + 127) / 128), dim3(128), 0, stream>>>(
        Sv, T0v, Ev, mu0, var0, muin, varin, C, L, A, B, W);
    onlnorm_pass3<<<g1, blk, 0, stream>>>(x, muin, varin, out, n, L);
}

// Round 10
// 199.749 us; speedup vs baseline: 4.1325x; 4.1325x over previous
//
#include <hip/hip_runtime.h>
#include <hip/hip_cooperative_groups.h>
#include <math.h>

namespace cg = cooperative_groups;

static constexpr float AFWD = 0.999f;
static constexpr float EPS  = 1e-5f;

typedef float vfloat4 __attribute__((ext_vector_type(4)));

// ================= fused cooperative kernel (R4 structure, R5 engine) =======
// Phase 1: per-(chunk,col4) aggregates {S,T0,E}, PF-8 load pipeline.
// Phase 2: per-column carry scan over C chunks (batched), writes muin/varin.
// Phase 3: replay with true carry, PF-8 pipeline, nt-stores (keep x in L3).
__global__ __launch_bounds__(256, 2) void onlnorm_fused(
    const float* __restrict__ x,
    const float* __restrict__ mu0, const float* __restrict__ var0,
    float* __restrict__ out,
    float* __restrict__ Sv, float* __restrict__ T0v, float* __restrict__ Ev,
    float* __restrict__ muin, float* __restrict__ varin,
    int n, int L, int C, float A, float B, float W)
{
    const float a = AFWD, b = 1.0f - AFWD, ab = AFWD * (1.0f - AFWD);
    const int chunk = blockIdx.y;
    const int col = (blockIdx.x * blockDim.x + threadIdx.x) * 4;
    const bool active = (col < L);
    constexpr int PF = 8;

    // ---------------- Phase 1: chunk-local aggregates ----------------
    if (active) {
        const float* xp = x + (size_t)chunk * (size_t)n * L + col;
        float m0=0.f,m1=0.f,m2=0.f,m3=0.f;
        float t0=0.f,t1=0.f,t2=0.f,t3=0.f;
        float e0=0.f,e1=0.f,e2=0.f,e3=0.f;

#define P1_STEP(xv)                                                   \
    do { float d;                                                     \
        d = (xv).x - m0; e0 += d; t0 = a*t0 + ab*d*d; m0 += b*d;      \
        d = (xv).y - m1; e1 += d; t1 = a*t1 + ab*d*d; m1 += b*d;      \
        d = (xv).z - m2; e2 += d; t2 = a*t2 + ab*d*d; m2 += b*d;      \
        d = (xv).w - m3; e3 += d; t3 = a*t3 + ab*d*d; m3 += b*d;      \
    } while (0)

        float4 buf[PF];
        #pragma unroll
        for (int j = 0; j < PF; ++j)
            buf[j] = *reinterpret_cast<const float4*>(xp + (size_t)j * L);
        for (int i0 = 0; i0 + PF < n; i0 += PF) {
            #pragma unroll
            for (int j = 0; j < PF; ++j) {
                const float4 xv = buf[j];
                buf[j] = *reinterpret_cast<const float4*>(xp + (size_t)(i0 + PF + j) * L);
                P1_STEP(xv);
            }
        }
        #pragma unroll
        for (int j = 0; j < PF; ++j) { const float4 xv = buf[j]; P1_STEP(xv); }
#undef P1_STEP

        const size_t base = (size_t)chunk * L + col;
        *reinterpret_cast<float4*>(Sv  + base) = make_float4(m0,m1,m2,m3);
        *reinterpret_cast<float4*>(T0v + base) = make_float4(t0,t1,t2,t3);
        *reinterpret_cast<float4*>(Ev  + base) = make_float4(e0,e1,e2,e3);
    }
    cg::this_grid().sync();

    // ---------------- Phase 2: per-column carry scan (16 blocks) ----------
    {
        const int bid = blockIdx.y * gridDim.x + blockIdx.x;
        const int nscan = (L + 255) / 256;                 // 16 blocks
        if (bid < nscan) {
            const int scol = bid * 256 + (int)threadIdx.x;
            if (scol < L) {
                float mu = mu0[scol], var = var0[scol];
                constexpr int BATCH = 16;
                float sb[BATCH], tb[BATCH], eb[BATCH];
                int c0 = 0;
                for (; c0 + BATCH <= C; c0 += BATCH) {
                    #pragma unroll
                    for (int j = 0; j < BATCH; ++j) {
                        const size_t idx = (size_t)(c0 + j) * L + scol;
                        sb[j] = Sv[idx]; tb[j] = T0v[idx]; eb[j] = Ev[idx];
                    }
                    #pragma unroll
                    for (int j = 0; j < BATCH; ++j) {
                        const size_t idx = (size_t)(c0 + j) * L + scol;
                        muin[idx]  = mu;
                        varin[idx] = var;
                        var = A*var + tb[j] - 2.0f*B*mu*eb[j] + W*mu*mu;
                        mu  = A*mu + sb[j];
                    }
                }
                for (; c0 < C; ++c0) {
                    const size_t idx = (size_t)c0 * L + scol;
                    muin[idx] = mu; varin[idx] = var;
                    const float s = Sv[idx], t = T0v[idx], e = Ev[idx];
                    var = A*var + t - 2.0f*B*mu*e + W*mu*mu;
                    mu  = A*mu + s;
                }
            }
        }
    }
    cg::this_grid().sync();

    // ---------------- Phase 3: replay with true carry, nt-stores ----------
    if (active) {
        const size_t cbase = (size_t)chunk * L + col;
        const float4 muv  = *reinterpret_cast<const float4*>(muin  + cbase);
        const float4 varv = *reinterpret_cast<const float4*>(varin + cbase);
        float m0=muv.x, m1=muv.y, m2=muv.z, m3=muv.w;
        float v0=varv.x, v1=varv.y, v2=varv.z, v3=varv.w;
        const float* xp = x   + (size_t)chunk * (size_t)n * L + col;
        float*       op = out + (size_t)chunk * (size_t)n * L + col;

#define P3_STEP(xv, row)                                                        \
    do { vfloat4 ov; float d;                                                   \
        d = (xv).x - m0; ov.x = d * rsqrtf(v0 + EPS); v0 = a*v0 + ab*d*d; m0 += b*d; \
        d = (xv).y - m1; ov.y = d * rsqrtf(v1 + EPS); v1 = a*v1 + ab*d*d; m1 += b*d; \
        d = (xv).z - m2; ov.z = d * rsqrtf(v2 + EPS); v2 = a*v2 + ab*d*d; m2 += b*d; \
        d = (xv).w - m3; ov.w = d * rsqrtf(v3 + EPS); v3 = a*v3 + ab*d*d; m3 += b*d; \
        __builtin_nontemporal_store(ov, reinterpret_cast<vfloat4*>(op + (size_t)(row) * L)); \
    } while (0)

        float4 buf[PF];
        #pragma unroll
        for (int j = 0; j < PF; ++j)
            buf[j] = *reinterpret_cast<const float4*>(xp + (size_t)j * L);
        for (int i0 = 0; i0 + PF < n; i0 += PF) {
            #pragma unroll
            for (int j = 0; j < PF; ++j) {
                const float4 xv = buf[j];
                buf[j] = *reinterpret_cast<const float4*>(xp + (size_t)(i0 + PF + j) * L);
                P3_STEP(xv, i0 + j);
            }
        }
        const int ie = n - PF;
        #pragma unroll
        for (int j = 0; j < PF; ++j) { const float4 xv = buf[j]; P3_STEP(xv, ie + j); }
#undef P3_STEP
    }
}

// ===================== fallback 3-pass path (R8, known-good) ================
__global__ __launch_bounds__(256) void onlnorm_pass1(
    const float* __restrict__ x, float* __restrict__ Sv,
    float* __restrict__ T0v, float* __restrict__ Ev, int n, int L)
{
    const int chunk = blockIdx.y;
    const int col = (blockIdx.x * blockDim.x + threadIdx.x) * 4;
    if (col >= L) return;
    const float a = AFWD, b = 1.0f - AFWD, ab = AFWD * (1.0f - AFWD);
    const float* xp = x + (size_t)chunk * (size_t)n * L + col;
    float m0=0.f,m1=0.f,m2=0.f,m3=0.f;
    float t0=0.f,t1=0.f,t2=0.f,t3=0.f;
    float e0=0.f,e1=0.f,e2=0.f,e3=0.f;
    constexpr int PF = 8;
#define P1_STEP(xv)                                                   \
    do { float d;                                                     \
        d = (xv).x - m0; e0 += d; t0 = a*t0 + ab*d*d; m0 += b*d;      \
        d = (xv).y - m1; e1 += d; t1 = a*t1 + ab*d*d; m1 += b*d;      \
        d = (xv).z - m2; e2 += d; t2 = a*t2 + ab*d*d; m2 += b*d;      \
        d = (xv).w - m3; e3 += d; t3 = a*t3 + ab*d*d; m3 += b*d;      \
    } while (0)
    if ((n % PF) == 0 && n >= 2 * PF) {
        float4 buf[PF];
        #pragma unroll
        for (int j = 0; j < PF; ++j)
            buf[j] = *reinterpret_cast<const float4*>(xp + (size_t)j * L);
        for (int i0 = 0; i0 + PF < n; i0 += PF) {
            #pragma unroll
            for (int j = 0; j < PF; ++j) {
                const float4 xv = buf[j];
                buf[j] = *reinterpret_cast<const float4*>(xp + (size_t)(i0 + PF + j) * L);
                P1_STEP(xv);
            }
        }
        #pragma unroll
        for (int j = 0; j < PF; ++j) { const float4 xv = buf[j]; P1_STEP(xv); }
    } else {
        for (int i = 0; i < n; ++i) {
            const float4 xv = *reinterpret_cast<const float4*>(xp + (size_t)i * L);
            P1_STEP(xv);
        }
    }
#undef P1_STEP
    const size_t base = (size_t)chunk * L + col;
    *reinterpret_cast<float4*>(Sv  + base) = make_float4(m0,m1,m2,m3);
    *reinterpret_cast<float4*>(T0v + base) = make_float4(t0,t1,t2,t3);
    *reinterpret_cast<float4*>(Ev  + base) = make_float4(e0,e1,e2,e3);
}

__global__ __launch_bounds__(128) void onlnorm_pass2(
    const float* __restrict__ Sv, const float* __restrict__ T0v,
    const float* __restrict__ Ev, const float* __restrict__ mu0,
    const float* __restrict__ var0, float* __restrict__ muin,
    float* __restrict__ varin, int C, int L, float A, float B, float W)
{
    const int col = blockIdx.x * blockDim.x + threadIdx.x;
    if (col >= L) return;
    float mu = mu0[col], var = var0[col];
    constexpr int BATCH = 32;
    float sb[BATCH], tb[BATCH], eb[BATCH];
    int c0 = 0;
    for (; c0 + BATCH <= C; c0 += BATCH) {
        #pragma unroll
        for (int j = 0; j < BATCH; ++j) {
            const size_t idx = (size_t)(c0 + j) * L + col;
            sb[j] = Sv[idx]; tb[j] = T0v[idx]; eb[j] = Ev[idx];
        }
        #pragma unroll
        for (int j = 0; j < BATCH; ++j) {
            const size_t idx = (size_t)(c0 + j) * L + col;
            muin[idx]  = mu;
            varin[idx] = var;
            var = A*var + tb[j] - 2.0f*B*mu*eb[j] + W*mu*mu;
            mu  = A*mu + sb[j];
        }
    }
    for (; c0 < C; ++c0) {
        const size_t idx = (size_t)c0 * L + col;
        muin[idx] = mu; varin[idx] = var;
        const float s = Sv[idx], t = T0v[idx], e = Ev[idx];
        var = A*var + t - 2.0f*B*mu*e + W*mu*mu;
        mu  = A*mu + s;
    }
}

__global__ __launch_bounds__(256) void onlnorm_pass3(
    const float* __restrict__ x, const float* __restrict__ muin,
    const float* __restrict__ varin, float* __restrict__ out, int n, int L)
{
    const int chunk = blockIdx.y;
    const int col = (blockIdx.x * blockDim.x + threadIdx.x) * 4;
    if (col >= L) return;
    const float a = AFWD, b = 1.0f - AFWD, ab = AFWD * (1.0f - AFWD);
    const size_t cbase = (size_t)chunk * L + col;
    const float4 muv  = *reinterpret_cast<const float4*>(muin  + cbase);
    const float4 varv = *reinterpret_cast<const float4*>(varin + cbase);
    float m0=muv.x, m1=muv.y, m2=muv.z, m3=muv.w;
    float v0=varv.x, v1=varv.y, v2=varv.z, v3=varv.w;
    const float* xp = x   + (size_t)chunk * (size_t)n * L + col;
    float*       op = out + (size_t)chunk * (size_t)n * L + col;
    constexpr int PF = 8;
#define P3_STEP(xv, row)                                                        \
    do { vfloat4 ov; float d;                                                   \
        d = (xv).x - m0; ov.x = d * rsqrtf(v0 + EPS); v0 = a*v0 + ab*d*d; m0 += b*d; \
        d = (xv).y - m1; ov.y = d * rsqrtf(v1 + EPS); v1 = a*v1 + ab*d*d; m1 += b*d; \
        d = (xv).z - m2; ov.z = d * rsqrtf(v2 + EPS); v2 = a*v2 + ab*d*d; m2 += b*d; \
        d = (xv).w - m3; ov.w = d * rsqrtf(v3 + EPS); v3 = a*v3 + ab*d*d; m3 += b*d; \
        __builtin_nontemporal_store(ov, reinterpret_cast<vfloat4*>(op + (size_t)(row) * L)); \
    } while (0)
    if ((n % PF) == 0 && n >= 2 * PF) {
        float4 buf[PF];
        #pragma unroll
        for (int j = 0; j < PF; ++j)
            buf[j] = *reinterpret_cast<const float4*>(xp + (size_t)j * L);
        for (int i0 = 0; i0 + PF < n; i0 += PF) {
            #pragma unroll
            for (int j = 0; j < PF; ++j) {
                const float4 xv = buf[j];
                buf[j] = *reinterpret_cast<const float4*>(xp + (size_t)(i0 + PF + j) * L);
                P3_STEP(xv, i0 + j);
            }
        }
        const int ie = n - PF;
        #pragma unroll
        for (int j = 0; j < PF; ++j) { const float4 xv = buf[j]; P3_STEP(xv, ie + j); }
    } else {
        for (int i = 0; i < n; ++i) {
            const float4 xv = *reinterpret_cast<const float4*>(xp + (size_t)i * L);
            P3_STEP(xv, i);
        }
    }
#undef P3_STEP
}

extern "C" void kernel_launch(void* const* d_in, const int* in_sizes, int n_in,
                              void* d_out, int out_size, void* d_ws, size_t ws_size,
                              hipStream_t stream) {
    const float* x    = (const float*)d_in[0];
    const float* mu0  = (const float*)d_in[1];
    const float* var0 = (const float*)d_in[2];
    float* out = (float*)d_out;

    const int L = in_sizes[1];          // 4096
    const int N = in_sizes[0] / L;      // 8192

    const int gx = (L / 4 + 255) / 256; // 4 colgroup-blocks per chunk

    // ---------- attempt: fused cooperative (512 blocks = 2/CU) ----------
    {
        int C = 128;
        while (C > 1 && (gx * C > 512 ||
                         (size_t)5 * (size_t)C * L * sizeof(float) > ws_size ||
                         (N % C) != 0 || ((N / C) % 16) != 0))
            C >>= 1;
        const int n = N / C;

        if ((n % 16) == 0 && gx * C <= 512 &&
            (size_t)5 * (size_t)C * L * sizeof(float) <= ws_size) {
            float* Sv    = (float*)d_ws;
            float* T0v   = Sv    + (size_t)C * L;
            float* Ev    = T0v   + (size_t)C * L;
            float* muin  = Ev    + (size_t)C * L;
            float* varin = muin  + (size_t)C * L;

            const double a  = (double)AFWD;
            const double An = pow(a, (double)n);
            float A = (float)An;
            float B = (float)(An * (1.0 - a));
            float W = (float)(An * (1.0 - An));

            dim3 grid(gx, C), block(256);
            int n_ = n, L_ = L, C_ = C;
            void* args[] = {
                (void*)&x, (void*)&mu0, (void*)&var0, (void*)&out,
                (void*)&Sv, (void*)&T0v, (void*)&Ev, (void*)&muin, (void*)&varin,
                (void*)&n_, (void*)&L_, (void*)&C_, (void*)&A, (void*)&B, (void*)&W
            };
            hipError_t err = hipLaunchCooperativeKernel((void*)onlnorm_fused,
                                                        grid, block, args, 0u, stream);
            if (err == hipSuccess) return;
        }
    }

    // ---------- fallback: R8 3-pass (known-good, 82 µs) ----------
    int C = 256;
    while (C > 1 && ((size_t)5 * (size_t)C * L * sizeof(float) > ws_size ||
                     (N % C) != 0))
        C >>= 1;
    const int n = N / C;

    float* Sv    = (float*)d_ws;
    float* T0v   = Sv    + (size_t)C * L;
    float* Ev    = T0v   + (size_t)C * L;
    float* muin  = Ev    + (size_t)C * L;
    float* varin = muin  + (size_t)C * L;

    const double a  = (double)AFWD;
    const double An = pow(a, (double)n);
    const float A = (float)An;
    const float B = (float)(An * (1.0 - a));
    const float W = (float)(An * (1.0 - An));

    const dim3 blk(256);
    const dim3 g1((L / 4 + 255) / 256, C);
    onlnorm_pass1<<<g1, blk, 0, stream>>>(x, Sv, T0v, Ev, n, L);
    onlnorm_pass2<<<dim3((L + 127) / 128), dim3(128), 0, stream>>>(
        Sv, T0v, Ev, mu0, var0, muin, varin, C, L, A, B, W);
    onlnorm_pass3<<<g1, blk, 0, stream>>>(x, muin, varin, out, n, L);
}

// Round 11
// 86.719 us; speedup vs baseline: 9.5188x; 2.3034x over previous
//
#include <hip/hip_runtime.h>
#include <math.h>

static constexpr float AFWD = 0.999f;
static constexpr float EPS  = 1e-5f;

typedef float vfloat4 __attribute__((ext_vector_type(4)));

// ---------------- Pass 1: full-row-slab blocks, PF-8 load pipeline ----------
// Block (bx, chunk): 1024 threads x 4 cols = 4096 cols per x-block. For
// L=4096, one block owns the whole row width -> its chunk is a fully
// contiguous n*16KB memory region (perfect page locality).
__global__ __launch_bounds__(1024) void onlnorm_pass1(
    const float* __restrict__ x, float* __restrict__ Sv,
    float* __restrict__ T0v, float* __restrict__ Ev, int n, int L)
{
    const int chunk = blockIdx.y;
    const int col = blockIdx.x * 4096 + (int)threadIdx.x * 4;
    if (col >= L) return;
    const float a = AFWD, b = 1.0f - AFWD, ab = AFWD * (1.0f - AFWD);
    const float* xp = x + (size_t)chunk * (size_t)n * L + col;

    float m0=0.f,m1=0.f,m2=0.f,m3=0.f;
    float t0=0.f,t1=0.f,t2=0.f,t3=0.f;
    float e0=0.f,e1=0.f,e2=0.f,e3=0.f;

    constexpr int PF = 8;

#define P1_STEP(xv)                                                   \
    do { float d;                                                     \
        d = (xv).x - m0; e0 += d; t0 = a*t0 + ab*d*d; m0 += b*d;      \
        d = (xv).y - m1; e1 += d; t1 = a*t1 + ab*d*d; m1 += b*d;      \
        d = (xv).z - m2; e2 += d; t2 = a*t2 + ab*d*d; m2 += b*d;      \
        d = (xv).w - m3; e3 += d; t3 = a*t3 + ab*d*d; m3 += b*d;      \
    } while (0)

    if ((n % PF) == 0 && n >= 2 * PF) {
        float4 buf[PF];
        #pragma unroll
        for (int j = 0; j < PF; ++j)
            buf[j] = *reinterpret_cast<const float4*>(xp + (size_t)j * L);
        for (int i0 = 0; i0 + PF < n; i0 += PF) {
            #pragma unroll
            for (int j = 0; j < PF; ++j) {
                const float4 xv = buf[j];
                buf[j] = *reinterpret_cast<const float4*>(xp + (size_t)(i0 + PF + j) * L);
                P1_STEP(xv);
            }
        }
        #pragma unroll
        for (int j = 0; j < PF; ++j) { const float4 xv = buf[j]; P1_STEP(xv); }
    } else {
        for (int i = 0; i < n; ++i) {
            const float4 xv = *reinterpret_cast<const float4*>(xp + (size_t)i * L);
            P1_STEP(xv);
        }
    }
#undef P1_STEP

    const size_t base = (size_t)chunk * L + col;
    *reinterpret_cast<float4*>(Sv  + base) = make_float4(m0,m1,m2,m3);
    *reinterpret_cast<float4*>(T0v + base) = make_float4(t0,t1,t2,t3);
    *reinterpret_cast<float4*>(Ev  + base) = make_float4(e0,e1,e2,e3);
}

// ---------------- Pass 2: per-column serial carry scan, BATCH=32 ------------
__global__ __launch_bounds__(128) void onlnorm_pass2(
    const float* __restrict__ Sv, const float* __restrict__ T0v,
    const float* __restrict__ Ev, const float* __restrict__ mu0,
    const float* __restrict__ var0, float* __restrict__ muin,
    float* __restrict__ varin, int C, int L, float A, float B, float W)
{
    const int col = blockIdx.x * blockDim.x + threadIdx.x;
    if (col >= L) return;
    float mu = mu0[col], var = var0[col];
    constexpr int BATCH = 32;
    float sb[BATCH], tb[BATCH], eb[BATCH];
    int c0 = 0;
    for (; c0 + BATCH <= C; c0 += BATCH) {
        #pragma unroll
        for (int j = 0; j < BATCH; ++j) {
            const size_t idx = (size_t)(c0 + j) * L + col;
            sb[j] = Sv[idx]; tb[j] = T0v[idx]; eb[j] = Ev[idx];
        }
        #pragma unroll
        for (int j = 0; j < BATCH; ++j) {
            const size_t idx = (size_t)(c0 + j) * L + col;
            muin[idx]  = mu;
            varin[idx] = var;
            var = A*var + tb[j] - 2.0f*B*mu*eb[j] + W*mu*mu;
            mu  = A*mu + sb[j];
        }
    }
    for (; c0 < C; ++c0) {
        const size_t idx = (size_t)c0 * L + col;
        muin[idx] = mu; varin[idx] = var;
        const float s = Sv[idx], t = T0v[idx], e = Ev[idx];
        var = A*var + t - 2.0f*B*mu*e + W*mu*mu;
        mu  = A*mu + s;
    }
}

// ---------------- Pass 3: full-row-slab replay, PF-8 pipeline, nt-stores ----
__global__ __launch_bounds__(1024) void onlnorm_pass3(
    const float* __restrict__ x, const float* __restrict__ muin,
    const float* __restrict__ varin, float* __restrict__ out, int n, int L)
{
    const int chunk = blockIdx.y;
    const int col = blockIdx.x * 4096 + (int)threadIdx.x * 4;
    if (col >= L) return;
    const float a = AFWD, b = 1.0f - AFWD, ab = AFWD * (1.0f - AFWD);
    const size_t cbase = (size_t)chunk * L + col;
    const float4 muv  = *reinterpret_cast<const float4*>(muin  + cbase);
    const float4 varv = *reinterpret_cast<const float4*>(varin + cbase);
    float m0=muv.x, m1=muv.y, m2=muv.z, m3=muv.w;
    float v0=varv.x, v1=varv.y, v2=varv.z, v3=varv.w;
    const float* xp = x   + (size_t)chunk * (size_t)n * L + col;
    float*       op = out + (size_t)chunk * (size_t)n * L + col;

    constexpr int PF = 8;

#define P3_STEP(xv, row)                                                        \
    do { vfloat4 ov; float d;                                                   \
        d = (xv).x - m0; ov.x = d * rsqrtf(v0 + EPS); v0 = a*v0 + ab*d*d; m0 += b*d; \
        d = (xv).y - m1; ov.y = d * rsqrtf(v1 + EPS); v1 = a*v1 + ab*d*d; m1 += b*d; \
        d = (xv).z - m2; ov.z = d * rsqrtf(v2 + EPS); v2 = a*v2 + ab*d*d; m2 += b*d; \
        d = (xv).w - m3; ov.w = d * rsqrtf(v3 + EPS); v3 = a*v3 + ab*d*d; m3 += b*d; \
        __builtin_nontemporal_store(ov, reinterpret_cast<vfloat4*>(op + (size_t)(row) * L)); \
    } while (0)

    if ((n % PF) == 0 && n >= 2 * PF) {
        float4 buf[PF];
        #pragma unroll
        for (int j = 0; j < PF; ++j)
            buf[j] = *reinterpret_cast<const float4*>(xp + (size_t)j * L);
        for (int i0 = 0; i0 + PF < n; i0 += PF) {
            #pragma unroll
            for (int j = 0; j < PF; ++j) {
                const float4 xv = buf[j];
                buf[j] = *reinterpret_cast<const float4*>(xp + (size_t)(i0 + PF + j) * L);
                P3_STEP(xv, i0 + j);
            }
        }
        const int ie = n - PF;
        #pragma unroll
        for (int j = 0; j < PF; ++j) { const float4 xv = buf[j]; P3_STEP(xv, ie + j); }
    } else {
        for (int i = 0; i < n; ++i) {
            const float4 xv = *reinterpret_cast<const float4*>(xp + (size_t)i * L);
            P3_STEP(xv, i);
        }
    }
#undef P3_STEP
}

extern "C" void kernel_launch(void* const* d_in, const int* in_sizes, int n_in,
                              void* d_out, int out_size, void* d_ws, size_t ws_size,
                              hipStream_t stream) {
    const float* x    = (const float*)d_in[0];
    const float* mu0  = (const float*)d_in[1];
    const float* var0 = (const float*)d_in[2];
    float* out = (float*)d_out;

    const int L = in_sizes[1];          // 4096
    const int N = in_sizes[0] / L;      // 8192

    // C=256 (n=32): ws fit (5 arrays of C*L f32), N % C == 0, (N/C) % 8 == 0.
    int C = 256;
    while (C > 1 && ((size_t)5 * (size_t)C * L * sizeof(float) > ws_size ||
                     (N % C) != 0))
        C >>= 1;
    const int n = N / C;

    float* Sv    = (float*)d_ws;
    float* T0v   = Sv    + (size_t)C * L;
    float* Ev    = T0v   + (size_t)C * L;
    float* muin  = Ev    + (size_t)C * L;
    float* varin = muin  + (size_t)C * L;

    const double a  = (double)AFWD;
    const double An = pow(a, (double)n);
    const float A = (float)An;
    const float B = (float)(An * (1.0 - a));
    const float W = (float)(An * (1.0 - An));

    // Full-row-slab streaming blocks: 1024 threads x 4 cols = 4096 cols/block.
    const dim3 blkS(1024);
    const dim3 gS((L + 4095) / 4096, C);

    onlnorm_pass1<<<gS, blkS, 0, stream>>>(x, Sv, T0v, Ev, n, L);
    onlnorm_pass2<<<dim3((L + 127) / 128), dim3(128), 0, stream>>>(
        Sv, T0v, Ev, mu0, var0, muin, varin, C, L, A, B, W);
    onlnorm_pass3<<<gS, blkS, 0, stream>>>(x, muin, varin, out, n, L);
}